// Round 8
// baseline (345.522 us; speedup 1.0000x reference)
//
#include <hip/hip_runtime.h>
#include <hip/hip_bf16.h>

#define N_NODES 100000
#define N_EDGES 1000000
#define N_GRAPHS 2048
#define F_IN 128
#define NEG_SLOPE 0.2f
#define E_TOT (N_EDGES + N_NODES)       // edges + self-loops
#define GEMM_BLOCKS 782                 // ceil(100000/128)
#define NODE_BLOCKS 391                 // ceil(100000/256)
#define EB 269                          // edge blocks = ceil(E_TOT/4096)
#define SCAT_BLOCKS 4297                // ceil(E_TOT/256), 1 edge/thread

typedef short  bf16x8 __attribute__((ext_vector_type(8)));
typedef float  f32x16 __attribute__((ext_vector_type(16)));

__device__ __forceinline__ short f2bf(float f) {      // RNE f32 -> bf16 bits
    unsigned u = __float_as_uint(f);
    unsigned r = (u + 0x7fffu + ((u >> 16) & 1u)) >> 16;
    return (short)r;
}
__device__ __forceinline__ float bf2f(short h) {
    return __uint_as_float(((unsigned)(unsigned short)h) << 16);
}

// ---- DPP helpers (ctrl is a template constant) ------------------------------
template <int CTRL>
__device__ __forceinline__ float dpp_add(float x) {
    return x + __int_as_float(__builtin_amdgcn_update_dpp(
        0, __float_as_int(x), CTRL, 0xf, 0xf, true));
}
__device__ __forceinline__ float full_sum64(float x) {
    x = dpp_add<0x111>(x);
    x = dpp_add<0x112>(x);
    x = dpp_add<0x114>(x);
    x = dpp_add<0x118>(x);
    x = dpp_add<0x142>(x);   // row_bcast:15
    x = dpp_add<0x143>(x);   // row_bcast:31
    return x;                // valid in lane 63
}
__device__ __forceinline__ float quad_sum(float x) {
    x = dpp_add<0xB1>(x);    // quad_perm [1,0,3,2]
    x = dpp_add<0x4E>(x);    // quad_perm [2,3,0,1]
    return x;
}

// ========== K1: xr/xlb = x @ [W_l|W_r] (split-bf16 MFMA)  +  node histogram ===
__global__ __launch_bounds__(256) void k_gemm_hist(const float* __restrict__ x,
                                                   const float* __restrict__ Wl,
                                                   const float* __restrict__ Wr,
                                                   const int* __restrict__ ei,
                                                   float* __restrict__ xr,
                                                   short* __restrict__ xlb,
                                                   int* __restrict__ deg) {
    __shared__ unsigned char smem[2 * 128 * 136 * 2];
    int tid = threadIdx.x;
    if (blockIdx.x >= GEMM_BLOCKS) {            // -------- histogram part
        int b = blockIdx.x - GEMM_BLOCKS;       // deg[] pre-zeroed by memset
        int e0 = b * 4096;
#pragma unroll
        for (int j = 0; j < 16; ++j) {
            int e = e0 + j * 256 + tid;
            if (e < E_TOT) {
                int d = (e < N_EDGES) ? ei[N_EDGES + e] : (e - N_EDGES);
                atomicAdd(&deg[d], 1);          // fire-and-forget
            }
        }
        return;
    }
    typedef short wt_t[128][136];
    wt_t* wt = (wt_t*)smem;                     // [hi/lo][n][k], +8 bf16 pad
    {   // ---- stage W transposed + split (once) ----
        int k  = tid >> 1;
        int cq = tid & 1;
        const float* Wsrc = cq ? Wr : Wl;
#pragma unroll
        for (int u = 0; u < 16; ++u) {
            int c0 = u * 4;
            float4 wv = *(const float4*)(Wsrc + (size_t)k * 64 + c0);
            float vv[4] = {wv.x, wv.y, wv.z, wv.w};
#pragma unroll
            for (int q = 0; q < 4; ++q) {
                int c = cq * 64 + c0 + q;
                short hi = f2bf(vv[q]);
                wt[0][c][k] = hi;
                wt[1][c][k] = f2bf(vv[q] - bf2f(hi));
            }
        }
    }
    __syncthreads();
    int lane = tid & 63, w = tid >> 6;
    int m = lane & 31, half = lane >> 5;
    int row = blockIdx.x * 128 + w * 32 + m;
    bool rv = row < N_NODES;
    const float* xrow = x + (size_t)(rv ? row : 0) * F_IN;
    f32x16 acc[4];
#pragma unroll
    for (int t = 0; t < 4; ++t)
#pragma unroll
        for (int i = 0; i < 16; ++i) acc[t][i] = 0.f;

#pragma unroll
    for (int kt = 0; kt < 8; ++kt) {            // K=16 steps
        int kb = kt * 16 + half * 8;
        float4 xa = rv ? *(const float4*)(xrow + kb)
                       : make_float4(0.f, 0.f, 0.f, 0.f);
        float4 xb = rv ? *(const float4*)(xrow + kb + 4)
                       : make_float4(0.f, 0.f, 0.f, 0.f);
        float xs[8] = {xa.x, xa.y, xa.z, xa.w, xb.x, xb.y, xb.z, xb.w};
        bf16x8 ahi, alo;
#pragma unroll
        for (int j = 0; j < 8; ++j) {
            short hi = f2bf(xs[j]);
            ahi[j] = hi;
            alo[j] = f2bf(xs[j] - bf2f(hi));
        }
#pragma unroll
        for (int t = 0; t < 4; ++t) {
            int n = t * 32 + m;
            bf16x8 bhi = *(const bf16x8*)&wt[0][n][kb];
            bf16x8 blo = *(const bf16x8*)&wt[1][n][kb];
            acc[t] = __builtin_amdgcn_mfma_f32_32x32x16_bf16(ahi, bhi, acc[t], 0, 0, 0);
            acc[t] = __builtin_amdgcn_mfma_f32_32x32x16_bf16(ahi, blo, acc[t], 0, 0, 0);
            acc[t] = __builtin_amdgcn_mfma_f32_32x32x16_bf16(alo, bhi, acc[t], 0, 0, 0);
        }
    }
    int r0 = blockIdx.x * 128 + w * 32 + 4 * half;
#pragma unroll
    for (int t = 0; t < 4; ++t)
#pragma unroll
        for (int reg = 0; reg < 16; ++reg) {
            int rr = r0 + (reg & 3) + 8 * (reg >> 2);
            if (rr < N_NODES) {
                if (t < 2)  // xl cols 0-63 -> bf16
                    xlb[(size_t)rr * 64 + t * 32 + m] = f2bf(acc[t][reg]);
                else        // xr cols 64-127 -> f32
                    xr[(size_t)rr * 64 + (t - 2) * 32 + m] = acc[t][reg];
            }
        }
}

// ========== K2: rowptr via redundant-prefix + block scan; batch bounds ========
__global__ __launch_bounds__(256) void k_rowptr_bounds(const int* __restrict__ deg,
                                                       const int* __restrict__ batch,
                                                       int* __restrict__ rowptr,
                                                       int* __restrict__ cursor,
                                                       int* __restrict__ start) {
    __shared__ int sctmp[256];
    __shared__ int sred[4];
    int tid = threadIdx.x;
    if (blockIdx.x < NODE_BLOCKS) {
        int b = blockIdx.x;
        int lim = b * 256;
        int s = 0;
        for (int i = tid; i < lim; i += 256) s += deg[i];
#pragma unroll
        for (int o = 1; o < 64; o <<= 1) s += __shfl_xor(s, o, 64);
        if ((tid & 63) == 0) sred[tid >> 6] = s;
        __syncthreads();
        int base = sred[0] + sred[1] + sred[2] + sred[3];
        int i = lim + tid;
        int v = (i < N_NODES) ? deg[i] : 0;
        sctmp[tid] = v;
        __syncthreads();
        for (int off = 1; off < 256; off <<= 1) {
            int xv = (tid >= off) ? sctmp[tid - off] : 0;
            __syncthreads();
            sctmp[tid] += xv;
            __syncthreads();
        }
        int excl = base + sctmp[tid] - v;       // exclusive prefix of deg
        if (i < N_NODES) { rowptr[i] = excl; cursor[i] = excl; }
        if (b == 0 && tid == 0) rowptr[N_NODES] = E_TOT;
    } else {
        int i = (blockIdx.x - NODE_BLOCKS) * 256 + tid;
        if (i >= N_NODES) return;
        int bi = batch[i];
        int bp = (i == 0) ? -1 : batch[i - 1];
        for (int g = bp + 1; g <= bi; ++g) start[g] = i;
        if (i == N_NODES - 1)
            for (int g = bi + 1; g <= N_GRAPHS; ++g) start[g] = N_NODES;
    }
}

// ========== K3: scatter — 1 edge/thread, big grid (r7 fix: occupancy 9%->full) =
__global__ __launch_bounds__(256) void k_scatter(const int* __restrict__ ei,
                                                 int* __restrict__ cursor,
                                                 int* __restrict__ sorted_src) {
    int e = blockIdx.x * 256 + threadIdx.x;
    if (e >= E_TOT) return;
    int s, d;
    if (e < N_EDGES) { s = ei[e]; d = ei[N_EDGES + e]; }
    else             { s = d = e - N_EDGES; }
    int pos = atomicAdd(&cursor[d], 1);
    sorted_src[pos] = s;
}

// ========== K5: GATv2 per dst — round-4-proven version, verbatim ==============
__global__ __launch_bounds__(256) void k_gat(const short* __restrict__ xlb,
                                             const float* __restrict__ xr,
                                             const int* __restrict__ rowptr,
                                             const int* __restrict__ sorted_src,
                                             const float* __restrict__ att,
                                             const float* __restrict__ bias,
                                             const float* __restrict__ w_rel,
                                             const float* __restrict__ w_root,
                                             float* __restrict__ hfeat,
                                             float* __restrict__ tbuf,
                                             float* __restrict__ rbuf) {
    int lane = threadIdx.x & 63;
    int du = __builtin_amdgcn_readfirstlane(blockIdx.x * 4 + (threadIdx.x >> 6));
    if (du >= N_NODES) return;
    int grp = lane >> 3, sub = lane & 7;
    float xr8[8], att8[8];
    {
        float4 a = *(const float4*)(xr + (size_t)du * 64 + sub * 8);
        float4 b = *(const float4*)(xr + (size_t)du * 64 + sub * 8 + 4);
        xr8[0]=a.x; xr8[1]=a.y; xr8[2]=a.z; xr8[3]=a.w;
        xr8[4]=b.x; xr8[5]=b.y; xr8[6]=b.z; xr8[7]=b.w;
        float4 c = *(const float4*)(att + sub * 8);
        float4 d = *(const float4*)(att + sub * 8 + 4);
        att8[0]=c.x; att8[1]=c.y; att8[2]=c.z; att8[3]=c.w;
        att8[4]=d.x; att8[5]=d.y; att8[6]=d.z; att8[7]=d.w;
    }
    int j0 = __builtin_amdgcn_readfirstlane(rowptr[du]);
    int j1 = __builtin_amdgcn_readfirstlane(rowptr[du + 1]);   // >= j0+1
    float wsum = 0.f;
    float acc8[8] = {0.f,0.f,0.f,0.f,0.f,0.f,0.f,0.f};
    for (int jc = j0; jc < j1; jc += 16) {
        int jA = jc + grp;
        int cjA = (jA > j1 - 1) ? j1 - 1 : jA;      // clamp: dup read, L1 hit
        int sA = sorted_src[cjA];
        bf16x8 xbA = *(const bf16x8*)(xlb + (size_t)(unsigned)sA * 64 + sub * 8);
        bool doB = (jc + 8 < j1);                   // wave-uniform
        int jB = jA + 8;
        bf16x8 xbB;
        if (doB) {                                  // issue 2nd gather early
            int cjB = (jB > j1 - 1) ? j1 - 1 : jB;
            int sB = sorted_src[cjB];
            xbB = *(const bf16x8*)(xlb + (size_t)(unsigned)sB * 64 + sub * 8);
        }
        {   // ---- half A (edges jc..jc+7) ----
            float xv[8];
#pragma unroll
            for (int j = 0; j < 8; ++j) xv[j] = bf2f(xbA[j]);
            float p = 0.f;
#pragma unroll
            for (int j = 0; j < 8; ++j) {
                float v = xv[j] + xr8[j];
                v = fmaxf(v, NEG_SLOPE * v);        // leaky-relu
                p += v * att8[j];
            }
            p = quad_sum(p);                        // per-head logit (quad == head)
            float w = (jA < j1) ? __expf(p) : 0.f;  // logits bounded; no max needed
            wsum += w;
#pragma unroll
            for (int j = 0; j < 8; ++j) acc8[j] += w * xv[j];
        }
        if (doB) {  // ---- half B (edges jc+8..jc+15) ----
            float xv[8];
#pragma unroll
            for (int j = 0; j < 8; ++j) xv[j] = bf2f(xbB[j]);
            float p = 0.f;
#pragma unroll
            for (int j = 0; j < 8; ++j) {
                float v = xv[j] + xr8[j];
                v = fmaxf(v, NEG_SLOPE * v);
                p += v * att8[j];
            }
            p = quad_sum(p);
            float w = (jB < j1) ? __expf(p) : 0.f;
            wsum += w;
#pragma unroll
            for (int j = 0; j < 8; ++j) acc8[j] += w * xv[j];
        }
    }
    // ---- issue epilogue parameter loads early (overlap with reduction) ----
    float4 bi0 = *(const float4*)(bias + sub * 8);
    float4 bi1 = *(const float4*)(bias + sub * 8 + 4);
    float4 wr0 = *(const float4*)(w_rel + sub * 8);
    float4 wr1 = *(const float4*)(w_rel + sub * 8 + 4);
    float4 wo0 = *(const float4*)(w_root + sub * 8);
    float4 wo1 = *(const float4*)(w_root + sub * 8 + 4);
    // ---- combine the 8 edge-groups (lanes sub, sub+8, ..., sub+56) ----
    wsum = dpp_add<0x128>(wsum);
    wsum += __shfl_xor(wsum, 16, 64);
    wsum += __shfl_xor(wsum, 32, 64);
#pragma unroll
    for (int j = 0; j < 8; ++j) {
        acc8[j] = dpp_add<0x128>(acc8[j]);
        acc8[j] += __shfl_xor(acc8[j], 16, 64);
        acc8[j] += __shfl_xor(acc8[j], 32, 64);
    }
    float inv = 1.0f / wsum;                        // one divide, 8 FMAs
    float bi8[8] = {bi0.x, bi0.y, bi0.z, bi0.w, bi1.x, bi1.y, bi1.z, bi1.w};
    float h8[8];
#pragma unroll
    for (int j = 0; j < 8; ++j)
        h8[j] = fmaf(acc8[j], inv, bi8[j]);
    if (grp == 0) {                             // lanes 0-7 store 64 channels
        float4 s0 = make_float4(h8[0], h8[1], h8[2], h8[3]);
        float4 s1 = make_float4(h8[4], h8[5], h8[6], h8[7]);
        *(float4*)(hfeat + (size_t)du * 64 + sub * 8)     = s0;
        *(float4*)(hfeat + (size_t)du * 64 + sub * 8 + 4) = s1;
    }
    float wrel8[8] = {wr0.x, wr0.y, wr0.z, wr0.w, wr1.x, wr1.y, wr1.z, wr1.w};
    float wroot8[8] = {wo0.x, wo0.y, wo0.z, wo0.w, wo1.x, wo1.y, wo1.z, wo1.w};
    float a = 0.f, b = 0.f;
#pragma unroll
    for (int j = 0; j < 8; ++j) {
        a += h8[j] * wrel8[j];
        b += h8[j] * wroot8[j];
    }
    a = full_sum64(a) * 0.125f;                 // 8 replicas -> /8
    b = full_sum64(b) * 0.125f;
    if (lane == 63) { tbuf[du] = a; rbuf[du] = b; }
}

// ========== K6: fused score + per-graph softmax-pool (block per graph) ========
__global__ __launch_bounds__(256) void k_pool(const int* __restrict__ rowptr,
                                              const int* __restrict__ sorted_src,
                                              const float* __restrict__ t,
                                              const float* __restrict__ r,
                                              const float* __restrict__ b_score,
                                              float* __restrict__ score,
                                              const float* __restrict__ h,
                                              const int* __restrict__ start,
                                              float* __restrict__ out) {
    __shared__ float sh[4];
    __shared__ float shacc[4][64];
    int g = blockIdx.x;
    int tid = threadIdx.x, w = tid >> 6, lane = tid & 63;
    int n0 = start[g], n1 = start[g + 1];
    int cnt = n1 - n0;
    if (cnt <= 0) { if (tid < 64) out[(size_t)g * 64 + tid] = 0.f; return; }
    float bsc = b_score[0];
    // --- phase 1: scores via sorted CSR, 4 threads per node + quad reduce
    for (int base = n0; base < n1; base += 64) {
        int i = base + (tid >> 2);
        float sum = 0.f;
        int jj0 = 0, jj1 = 0;
        if (i < n1) { jj0 = rowptr[i]; jj1 = rowptr[i + 1]; }
        for (int j = jj0 + (tid & 3); j < jj1; j += 4)
            sum += t[sorted_src[j]];
        sum = quad_sum(sum);
        if (i < n1 && (tid & 3) == 0)
            score[i] = sum - t[i] + r[i] + bsc;
    }
    __syncthreads();
    // --- phase 2a: max, then overwrite score with exp(score-m); sum exps
    float m = -1e30f;
    for (int i = n0 + tid; i < n1; i += 256) m = fmaxf(m, score[i]);
#pragma unroll
    for (int o = 32; o; o >>= 1) m = fmaxf(m, __shfl_xor(m, o, 64));
    if (lane == 0) sh[w] = m;
    __syncthreads();
    m = fmaxf(fmaxf(sh[0], sh[1]), fmaxf(sh[2], sh[3]));
    __syncthreads();
    float ssum = 0.f;
    for (int i = n0 + tid; i < n1; i += 256) {
        float e = __expf(score[i] - m);
        score[i] = e;
        ssum += e;
    }
#pragma unroll
    for (int o = 32; o; o >>= 1) ssum += __shfl_xor(ssum, o, 64);
    if (lane == 0) sh[w] = ssum;
    __syncthreads();
    ssum = sh[0] + sh[1] + sh[2] + sh[3];
    // --- phase 2b: weighted feature accumulation (no redundant exps)
    float acc = 0.f;
    for (int i = n0 + w; i < n1; i += 4)
        acc += score[i] * h[(size_t)i * 64 + lane];
    shacc[w][lane] = acc;
    __syncthreads();
    if (w == 0) {
        float tot = shacc[0][lane] + shacc[1][lane] + shacc[2][lane] + shacc[3][lane];
        out[(size_t)g * 64 + lane] = tot * (1.f + 1.f / (float)cnt) / ssum;
    }
}

extern "C" void kernel_launch(void* const* d_in, const int* in_sizes, int n_in,
                              void* d_out, int out_size, void* d_ws, size_t ws_size,
                              hipStream_t stream) {
    const float* x      = (const float*)d_in[0];
    const int*   ei     = (const int*)d_in[1];
    const int*   batch  = (const int*)d_in[2];
    const float* Wl     = (const float*)d_in[3];
    const float* Wr     = (const float*)d_in[4];
    const float* att    = (const float*)d_in[5];
    const float* bias   = (const float*)d_in[6];
    const float* w_rel  = (const float*)d_in[7];
    const float* w_root = (const float*)d_in[8];
    const float* b_sc   = (const float*)d_in[9];

    char* ws = (char*)d_ws;
    size_t off = 0;
    auto alloc = [&](size_t bytes) { void* p = ws + off; off += (bytes + 255) & ~255ull; return p; };
    float* xr         = (float*)alloc((size_t)N_NODES * 64 * 4);        // 25.6 MB
    short* xlb        = (short*)alloc((size_t)N_NODES * 64 * 2);        // 12.8 MB
    float* hfeat      = (float*)alloc((size_t)N_NODES * 64 * 4);        // 25.6 MB
    int*   sorted_src = (int*)  alloc((size_t)(E_TOT + 16) * 4);        // 4.4 MB
    int*   rowptr     = (int*)  alloc((size_t)(N_NODES + 1) * 4);
    int*   cursor     = (int*)  alloc((size_t)N_NODES * 4);
    int*   deg        = (int*)  alloc((size_t)N_NODES * 4);
    float* tbuf       = (float*)alloc((size_t)N_NODES * 4);
    float* rbuf       = (float*)alloc((size_t)N_NODES * 4);
    float* score      = (float*)alloc((size_t)N_NODES * 4);
    int*   start      = (int*)  alloc((size_t)(N_GRAPHS + 1) * 4);

    hipMemsetAsync(deg, 0, (size_t)N_NODES * 4, stream);
    k_gemm_hist    <<<GEMM_BLOCKS + EB, 256, 0, stream>>>(x, Wl, Wr, ei, xr, xlb, deg);
    k_rowptr_bounds<<<NODE_BLOCKS * 2, 256, 0, stream>>>(deg, batch, rowptr, cursor, start);
    k_scatter      <<<SCAT_BLOCKS, 256, 0, stream>>>(ei, cursor, sorted_src);
    k_gat          <<<(N_NODES + 3) / 4, 256, 0, stream>>>(xlb, xr, rowptr, sorted_src, att, bias,
                                                           w_rel, w_root, hfeat, tbuf, rbuf);
    k_pool         <<<N_GRAPHS, 256, 0, stream>>>(rowptr, sorted_src, tbuf, rbuf, b_sc,
                                                  score, hfeat, start, (float*)d_out);
}

// Round 9
// 220.543 us; speedup vs baseline: 1.5667x; 1.5667x over previous
//
#include <hip/hip_runtime.h>
#include <hip/hip_bf16.h>

#define N_NODES 100000
#define N_EDGES 1000000
#define N_GRAPHS 2048
#define F_IN 128
#define NEG_SLOPE 0.2f
#define E_TOT (N_EDGES + N_NODES)       // edges + self-loops
#define GEMM_BLOCKS 391                 // ceil(100000/256), 2 row-tiles/block
#define NODE_BLOCKS 391                 // ceil(100000/256)
#define NB 1563                         // coarse buckets = ceil(N_NODES/64)
#define EB 269                          // edge blocks = ceil(E_TOT/4096)
#define EB_PAD 272
#define CPW_BLOCKS 391                  // ceil(NB/4) wave-per-bucket scan blocks

typedef short  bf16x8 __attribute__((ext_vector_type(8)));
typedef float  f32x16 __attribute__((ext_vector_type(16)));

__device__ __forceinline__ short f2bf(float f) {      // RNE f32 -> bf16 bits
    unsigned u = __float_as_uint(f);
    unsigned r = (u + 0x7fffu + ((u >> 16) & 1u)) >> 16;
    return (short)r;
}
__device__ __forceinline__ float bf2f(short h) {
    return __uint_as_float(((unsigned)(unsigned short)h) << 16);
}

// ---- DPP helpers (ctrl is a template constant) ------------------------------
template <int CTRL>
__device__ __forceinline__ float dpp_add(float x) {
    return x + __int_as_float(__builtin_amdgcn_update_dpp(
        0, __float_as_int(x), CTRL, 0xf, 0xf, true));
}
__device__ __forceinline__ float full_sum64(float x) {
    x = dpp_add<0x111>(x);
    x = dpp_add<0x112>(x);
    x = dpp_add<0x114>(x);
    x = dpp_add<0x118>(x);
    x = dpp_add<0x142>(x);   // row_bcast:15
    x = dpp_add<0x143>(x);   // row_bcast:31
    return x;                // valid in lane 63
}
__device__ __forceinline__ float quad_sum(float x) {
    x = dpp_add<0xB1>(x);    // quad_perm [1,0,3,2]
    x = dpp_add<0x4E>(x);    // quad_perm [2,3,0,1]
    return x;
}

// ========== K1: xr/xlb = x @ [W_l|W_r] (split-bf16 MFMA)  +  coarse hist ======
// r9: 391 blocks x TWO 128-row tiles — W staged into LDS once per block,
// halving the staging overhead (it was done 782x in r4 for the same W).
__global__ __launch_bounds__(256) void k_gemm_bhist(const float* __restrict__ x,
                                                    const float* __restrict__ Wl,
                                                    const float* __restrict__ Wr,
                                                    const int* __restrict__ ei,
                                                    float* __restrict__ xr,
                                                    short* __restrict__ xlb,
                                                    int* __restrict__ bhist) {
    __shared__ unsigned char smem[2 * 128 * 136 * 2];   // overlaid: wt | lh
    int tid = threadIdx.x;
    if (blockIdx.x >= GEMM_BLOCKS) {            // -------- histogram part
        int* lh = (int*)smem;
        int b = blockIdx.x - GEMM_BLOCKS;
        for (int i = tid; i < NB; i += 256) lh[i] = 0;
        __syncthreads();
        int e0 = b * 4096;
#pragma unroll
        for (int j = 0; j < 16; ++j) {
            int e = e0 + j * 256 + tid;
            if (e < E_TOT) {
                int d = (e < N_EDGES) ? ei[N_EDGES + e] : (e - N_EDGES);
                atomicAdd(&lh[d >> 6], 1);
            }
        }
        __syncthreads();
        for (int i = tid; i < NB; i += 256)
            bhist[(size_t)i * EB_PAD + b] = lh[i];  // bucket-major
        return;
    }
    typedef short wt_t[128][136];
    wt_t* wt = (wt_t*)smem;                     // [hi/lo][n][k], +8 bf16 pad
    {   // ---- stage W transposed + split (ONCE per block, reused 2 tiles) ----
        int k  = tid >> 1;
        int cq = tid & 1;
        const float* Wsrc = cq ? Wr : Wl;
#pragma unroll
        for (int u = 0; u < 16; ++u) {
            int c0 = u * 4;
            float4 wv = *(const float4*)(Wsrc + (size_t)k * 64 + c0);
            float vv[4] = {wv.x, wv.y, wv.z, wv.w};
#pragma unroll
            for (int q = 0; q < 4; ++q) {
                int c = cq * 64 + c0 + q;
                short hi = f2bf(vv[q]);
                wt[0][c][k] = hi;
                wt[1][c][k] = f2bf(vv[q] - bf2f(hi));
            }
        }
    }
    __syncthreads();
    int lane = tid & 63, w = tid >> 6;
    int m = lane & 31, half = lane >> 5;
#pragma unroll
    for (int tile = 0; tile < 2; ++tile) {
        int rowbase = blockIdx.x * 256 + tile * 128;
        int row = rowbase + w * 32 + m;
        bool rv = row < N_NODES;
        const float* xrow = x + (size_t)(rv ? row : 0) * F_IN;
        f32x16 acc[4];
#pragma unroll
        for (int t = 0; t < 4; ++t)
#pragma unroll
            for (int i = 0; i < 16; ++i) acc[t][i] = 0.f;

#pragma unroll
        for (int kt = 0; kt < 8; ++kt) {        // K=16 steps
            int kb = kt * 16 + half * 8;
            float4 xa = rv ? *(const float4*)(xrow + kb)
                           : make_float4(0.f, 0.f, 0.f, 0.f);
            float4 xb = rv ? *(const float4*)(xrow + kb + 4)
                           : make_float4(0.f, 0.f, 0.f, 0.f);
            float xs[8] = {xa.x, xa.y, xa.z, xa.w, xb.x, xb.y, xb.z, xb.w};
            bf16x8 ahi, alo;
#pragma unroll
            for (int j = 0; j < 8; ++j) {
                short hi = f2bf(xs[j]);
                ahi[j] = hi;
                alo[j] = f2bf(xs[j] - bf2f(hi));
            }
#pragma unroll
            for (int t = 0; t < 4; ++t) {
                int n = t * 32 + m;
                bf16x8 bhi = *(const bf16x8*)&wt[0][n][kb];
                bf16x8 blo = *(const bf16x8*)&wt[1][n][kb];
                acc[t] = __builtin_amdgcn_mfma_f32_32x32x16_bf16(ahi, bhi, acc[t], 0, 0, 0);
                acc[t] = __builtin_amdgcn_mfma_f32_32x32x16_bf16(ahi, blo, acc[t], 0, 0, 0);
                acc[t] = __builtin_amdgcn_mfma_f32_32x32x16_bf16(alo, bhi, acc[t], 0, 0, 0);
            }
        }
        int r0 = rowbase + w * 32 + 4 * half;
#pragma unroll
        for (int t = 0; t < 4; ++t)
#pragma unroll
            for (int reg = 0; reg < 16; ++reg) {
                int rr = r0 + (reg & 3) + 8 * (reg >> 2);
                if (rr < N_NODES) {
                    if (t < 2)  // xl cols 0-63 -> bf16
                        xlb[(size_t)rr * 64 + t * 32 + m] = f2bf(acc[t][reg]);
                    else        // xr cols 64-127 -> f32
                        xr[(size_t)rr * 64 + (t - 2) * 32 + m] = acc[t][reg];
                }
            }
    }
}

// ========== K2: wave-per-bucket exclusive scan over blocks + bounds ===========
__global__ __launch_bounds__(256) void k_colprefix_bounds(int* __restrict__ bhist,
                                                          int* __restrict__ colsum,
                                                          const int* __restrict__ batch,
                                                          int* __restrict__ start) {
    if (blockIdx.x < CPW_BLOCKS) {
        int wv = blockIdx.x * 4 + (threadIdx.x >> 6);   // bucket id, wave-uniform
        if (wv >= NB) return;
        int lane = threadIdx.x & 63;
        int* row = bhist + (size_t)wv * EB_PAD;
        int carry = 0;
        for (int base = 0; base < EB; base += 64) {
            int idx = base + lane;
            int v = (idx < EB) ? row[idx] : 0;
            int inc = v;
#pragma unroll
            for (int o = 1; o < 64; o <<= 1) {
                int t = __shfl_up(inc, o, 64);
                if (lane >= o) inc += t;
            }
            int tot = __shfl(inc, 63, 64);
            if (idx < EB) row[idx] = carry + inc - v;   // exclusive prefix
            carry += tot;
        }
        if (lane == 0) colsum[wv] = carry;
    } else {
        int i = (blockIdx.x - CPW_BLOCKS) * 256 + threadIdx.x;
        if (i >= N_NODES) return;
        int bi = batch[i];
        int bp = (i == 0) ? -1 : batch[i - 1];
        for (int g = bp + 1; g <= bi; ++g) start[g] = i;
        if (i == N_NODES - 1)
            for (int g = bi + 1; g <= N_GRAPHS; ++g) start[g] = N_NODES;
    }
}

// ========== K3: scatter edges into coarse buckets; redundant colbase scan =====
__global__ __launch_bounds__(256) void k_bscatter(const int* __restrict__ ei,
                                                  const int* __restrict__ bhist,
                                                  const int* __restrict__ colsum,
                                                  int* __restrict__ colbase,
                                                  int* __restrict__ bpack) {
    __shared__ int lh[NB];
    __shared__ int cb[NB + 1];
    __shared__ int sctmp[256];
    int tid = threadIdx.x, b = blockIdx.x;
    {   // redundant exclusive scan of colsum -> cb (per block, wall-hidden)
        int v[7]; int s = 0;
#pragma unroll
        for (int k = 0; k < 7; ++k) {
            int idx = tid * 7 + k;
            v[k] = (idx < NB) ? colsum[idx] : 0;
            s += v[k];
        }
        sctmp[tid] = s; __syncthreads();
        for (int off = 1; off < 256; off <<= 1) {
            int xv = (tid >= off) ? sctmp[tid - off] : 0;
            __syncthreads();
            sctmp[tid] += xv;
            __syncthreads();
        }
        int run = sctmp[tid] - s;
#pragma unroll
        for (int k = 0; k < 7; ++k) {
            int idx = tid * 7 + k;
            if (idx <= NB) cb[idx] = run;
            run += v[k];
        }
    }
    for (int i = tid; i < NB; i += 256) lh[i] = 0;
    __syncthreads();
    if (b == 0)                                 // publish colbase for k_fine
        for (int i = tid; i <= NB; i += 256) colbase[i] = cb[i];
    int e0 = b * 4096;
#pragma unroll
    for (int j = 0; j < 16; ++j) {
        int e = e0 + j * 256 + tid;
        if (e < E_TOT) {
            int s, d;
            if (e < N_EDGES) { s = ei[e]; d = ei[N_EDGES + e]; }
            else             { s = d = e - N_EDGES; }
            int bk = d >> 6;
            int lr = atomicAdd(&lh[bk], 1);
            int pos = cb[bk] + bhist[(size_t)bk * EB_PAD + b] + lr;
            bpack[pos] = s | ((d & 63) << 17);  // src in 17 bits, local dst in 6
        }
    }
}

// ========== K4: per-bucket fine grouping -> rowptr + sorted_src ===============
__global__ __launch_bounds__(256) void k_fine(const int* __restrict__ bpack,
                                              const int* __restrict__ colbase,
                                              int* __restrict__ rowptr,
                                              int* __restrict__ sorted_src) {
    __shared__ int fcnt[64];
    __shared__ int foff[64];
    int i = blockIdx.x, tid = threadIdx.x;
    if (i == 0 && tid < 16) sorted_src[E_TOT + tid] = 0;   // pad (harmless)
    int cb0 = colbase[i], cb1 = colbase[i + 1];
    if (tid < 64) fcnt[tid] = 0;
    __syncthreads();
    for (int e = cb0 + tid; e < cb1; e += 256)
        atomicAdd(&fcnt[bpack[e] >> 17], 1);
    __syncthreads();
    if (tid < 64) {                             // wave 0: scan of 64 counts
        int v = fcnt[tid];
        int inc = v;
#pragma unroll
        for (int o = 1; o < 64; o <<= 1) {
            int t = __shfl_up(inc, o, 64);
            if (tid >= o) inc += t;
        }
        int excl = inc - v;
        foff[tid] = excl;
        int node = i * 64 + tid;
        if (node <= N_NODES) rowptr[node] = cb0 + excl;
    }
    __syncthreads();
    for (int e = cb0 + tid; e < cb1; e += 256) {
        int w = bpack[e];
        int lr = atomicAdd(&foff[w >> 17], 1);
        sorted_src[cb0 + lr] = w & 131071;
    }
}

// ========== K5: GATv2 per dst — round-4-proven version, verbatim ==============
__global__ __launch_bounds__(256) void k_gat(const short* __restrict__ xlb,
                                             const float* __restrict__ xr,
                                             const int* __restrict__ rowptr,
                                             const int* __restrict__ sorted_src,
                                             const float* __restrict__ att,
                                             const float* __restrict__ bias,
                                             const float* __restrict__ w_rel,
                                             const float* __restrict__ w_root,
                                             float* __restrict__ hfeat,
                                             float* __restrict__ tbuf,
                                             float* __restrict__ rbuf) {
    int lane = threadIdx.x & 63;
    int du = __builtin_amdgcn_readfirstlane(blockIdx.x * 4 + (threadIdx.x >> 6));
    if (du >= N_NODES) return;
    int grp = lane >> 3, sub = lane & 7;
    float xr8[8], att8[8];
    {
        float4 a = *(const float4*)(xr + (size_t)du * 64 + sub * 8);
        float4 b = *(const float4*)(xr + (size_t)du * 64 + sub * 8 + 4);
        xr8[0]=a.x; xr8[1]=a.y; xr8[2]=a.z; xr8[3]=a.w;
        xr8[4]=b.x; xr8[5]=b.y; xr8[6]=b.z; xr8[7]=b.w;
        float4 c = *(const float4*)(att + sub * 8);
        float4 d = *(const float4*)(att + sub * 8 + 4);
        att8[0]=c.x; att8[1]=c.y; att8[2]=c.z; att8[3]=c.w;
        att8[4]=d.x; att8[5]=d.y; att8[6]=d.z; att8[7]=d.w;
    }
    int j0 = __builtin_amdgcn_readfirstlane(rowptr[du]);
    int j1 = __builtin_amdgcn_readfirstlane(rowptr[du + 1]);   // >= j0+1
    float wsum = 0.f;
    float acc8[8] = {0.f,0.f,0.f,0.f,0.f,0.f,0.f,0.f};
    for (int jc = j0; jc < j1; jc += 16) {
        int jA = jc + grp;
        int cjA = (jA > j1 - 1) ? j1 - 1 : jA;      // clamp: dup read, L1 hit
        int sA = sorted_src[cjA];
        bf16x8 xbA = *(const bf16x8*)(xlb + (size_t)(unsigned)sA * 64 + sub * 8);
        bool doB = (jc + 8 < j1);                   // wave-uniform
        int jB = jA + 8;
        bf16x8 xbB;
        if (doB) {                                  // issue 2nd gather early
            int cjB = (jB > j1 - 1) ? j1 - 1 : jB;
            int sB = sorted_src[cjB];
            xbB = *(const bf16x8*)(xlb + (size_t)(unsigned)sB * 64 + sub * 8);
        }
        {   // ---- half A (edges jc..jc+7) ----
            float xv[8];
#pragma unroll
            for (int j = 0; j < 8; ++j) xv[j] = bf2f(xbA[j]);
            float p = 0.f;
#pragma unroll
            for (int j = 0; j < 8; ++j) {
                float v = xv[j] + xr8[j];
                v = fmaxf(v, NEG_SLOPE * v);        // leaky-relu
                p += v * att8[j];
            }
            p = quad_sum(p);                        // per-head logit (quad == head)
            float w = (jA < j1) ? __expf(p) : 0.f;  // logits bounded; no max needed
            wsum += w;
#pragma unroll
            for (int j = 0; j < 8; ++j) acc8[j] += w * xv[j];
        }
        if (doB) {  // ---- half B (edges jc+8..jc+15) ----
            float xv[8];
#pragma unroll
            for (int j = 0; j < 8; ++j) xv[j] = bf2f(xbB[j]);
            float p = 0.f;
#pragma unroll
            for (int j = 0; j < 8; ++j) {
                float v = xv[j] + xr8[j];
                v = fmaxf(v, NEG_SLOPE * v);
                p += v * att8[j];
            }
            p = quad_sum(p);
            float w = (jB < j1) ? __expf(p) : 0.f;
            wsum += w;
#pragma unroll
            for (int j = 0; j < 8; ++j) acc8[j] += w * xv[j];
        }
    }
    // ---- issue epilogue parameter loads early (overlap with reduction) ----
    float4 bi0 = *(const float4*)(bias + sub * 8);
    float4 bi1 = *(const float4*)(bias + sub * 8 + 4);
    float4 wr0 = *(const float4*)(w_rel + sub * 8);
    float4 wr1 = *(const float4*)(w_rel + sub * 8 + 4);
    float4 wo0 = *(const float4*)(w_root + sub * 8);
    float4 wo1 = *(const float4*)(w_root + sub * 8 + 4);
    // ---- combine the 8 edge-groups (lanes sub, sub+8, ..., sub+56) ----
    wsum = dpp_add<0x128>(wsum);
    wsum += __shfl_xor(wsum, 16, 64);
    wsum += __shfl_xor(wsum, 32, 64);
#pragma unroll
    for (int j = 0; j < 8; ++j) {
        acc8[j] = dpp_add<0x128>(acc8[j]);
        acc8[j] += __shfl_xor(acc8[j], 16, 64);
        acc8[j] += __shfl_xor(acc8[j], 32, 64);
    }
    float inv = 1.0f / wsum;                        // one divide, 8 FMAs
    float bi8[8] = {bi0.x, bi0.y, bi0.z, bi0.w, bi1.x, bi1.y, bi1.z, bi1.w};
    float h8[8];
#pragma unroll
    for (int j = 0; j < 8; ++j)
        h8[j] = fmaf(acc8[j], inv, bi8[j]);
    if (grp == 0) {                             // lanes 0-7 store 64 channels
        float4 s0 = make_float4(h8[0], h8[1], h8[2], h8[3]);
        float4 s1 = make_float4(h8[4], h8[5], h8[6], h8[7]);
        *(float4*)(hfeat + (size_t)du * 64 + sub * 8)     = s0;
        *(float4*)(hfeat + (size_t)du * 64 + sub * 8 + 4) = s1;
    }
    float wrel8[8] = {wr0.x, wr0.y, wr0.z, wr0.w, wr1.x, wr1.y, wr1.z, wr1.w};
    float wroot8[8] = {wo0.x, wo0.y, wo0.z, wo0.w, wo1.x, wo1.y, wo1.z, wo1.w};
    float a = 0.f, b = 0.f;
#pragma unroll
    for (int j = 0; j < 8; ++j) {
        a += h8[j] * wrel8[j];
        b += h8[j] * wroot8[j];
    }
    a = full_sum64(a) * 0.125f;                 // 8 replicas -> /8
    b = full_sum64(b) * 0.125f;
    if (lane == 63) { tbuf[du] = a; rbuf[du] = b; }
}

// ========== K6: fused score + per-graph softmax-pool (block per graph) ========
__global__ __launch_bounds__(256) void k_pool(const int* __restrict__ rowptr,
                                              const int* __restrict__ sorted_src,
                                              const float* __restrict__ t,
                                              const float* __restrict__ r,
                                              const float* __restrict__ b_score,
                                              float* __restrict__ score,
                                              const float* __restrict__ h,
                                              const int* __restrict__ start,
                                              float* __restrict__ out) {
    __shared__ float sh[4];
    __shared__ float shacc[4][64];
    int g = blockIdx.x;
    int tid = threadIdx.x, w = tid >> 6, lane = tid & 63;
    int n0 = start[g], n1 = start[g + 1];
    int cnt = n1 - n0;
    if (cnt <= 0) { if (tid < 64) out[(size_t)g * 64 + tid] = 0.f; return; }
    float bsc = b_score[0];
    // --- phase 1: scores via sorted CSR, 4 threads per node + quad reduce
    for (int base = n0; base < n1; base += 64) {
        int i = base + (tid >> 2);
        float sum = 0.f;
        int jj0 = 0, jj1 = 0;
        if (i < n1) { jj0 = rowptr[i]; jj1 = rowptr[i + 1]; }
        for (int j = jj0 + (tid & 3); j < jj1; j += 4)
            sum += t[sorted_src[j]];
        sum = quad_sum(sum);
        if (i < n1 && (tid & 3) == 0)
            score[i] = sum - t[i] + r[i] + bsc;
    }
    __syncthreads();
    // --- phase 2a: max, then overwrite score with exp(score-m); sum exps
    float m = -1e30f;
    for (int i = n0 + tid; i < n1; i += 256) m = fmaxf(m, score[i]);
#pragma unroll
    for (int o = 32; o; o >>= 1) m = fmaxf(m, __shfl_xor(m, o, 64));
    if (lane == 0) sh[w] = m;
    __syncthreads();
    m = fmaxf(fmaxf(sh[0], sh[1]), fmaxf(sh[2], sh[3]));
    __syncthreads();
    float ssum = 0.f;
    for (int i = n0 + tid; i < n1; i += 256) {
        float e = __expf(score[i] - m);
        score[i] = e;
        ssum += e;
    }
#pragma unroll
    for (int o = 32; o; o >>= 1) ssum += __shfl_xor(ssum, o, 64);
    if (lane == 0) sh[w] = ssum;
    __syncthreads();
    ssum = sh[0] + sh[1] + sh[2] + sh[3];
    // --- phase 2b: weighted feature accumulation (no redundant exps)
    float acc = 0.f;
    for (int i = n0 + w; i < n1; i += 4)
        acc += score[i] * h[(size_t)i * 64 + lane];
    shacc[w][lane] = acc;
    __syncthreads();
    if (w == 0) {
        float tot = shacc[0][lane] + shacc[1][lane] + shacc[2][lane] + shacc[3][lane];
        out[(size_t)g * 64 + lane] = tot * (1.f + 1.f / (float)cnt) / ssum;
    }
}

extern "C" void kernel_launch(void* const* d_in, const int* in_sizes, int n_in,
                              void* d_out, int out_size, void* d_ws, size_t ws_size,
                              hipStream_t stream) {
    const float* x      = (const float*)d_in[0];
    const int*   ei     = (const int*)d_in[1];
    const int*   batch  = (const int*)d_in[2];
    const float* Wl     = (const float*)d_in[3];
    const float* Wr     = (const float*)d_in[4];
    const float* att    = (const float*)d_in[5];
    const float* bias   = (const float*)d_in[6];
    const float* w_rel  = (const float*)d_in[7];
    const float* w_root = (const float*)d_in[8];
    const float* b_sc   = (const float*)d_in[9];

    char* ws = (char*)d_ws;
    size_t off = 0;
    auto alloc = [&](size_t bytes) { void* p = ws + off; off += (bytes + 255) & ~255ull; return p; };
    float* xr         = (float*)alloc((size_t)N_NODES * 64 * 4);        // 25.6 MB
    short* xlb        = (short*)alloc((size_t)N_NODES * 64 * 2);        // 12.8 MB
    float* hfeat      = (float*)alloc((size_t)N_NODES * 64 * 4);        // 25.6 MB
    int*   bhist      = (int*)hfeat;   // alias: bhist dead before k_gat writes hfeat
    int*   bpack      = (int*)  alloc((size_t)E_TOT * 4);               // 4.4 MB
    int*   sorted_src = (int*)  alloc((size_t)(E_TOT + 16) * 4);        // +16 pad
    int*   rowptr     = (int*)  alloc((size_t)(N_NODES + 1) * 4);
    int*   colsum     = (int*)  alloc((size_t)NB * 4);
    int*   colbase    = (int*)  alloc((size_t)(NB + 1) * 4);
    float* tbuf       = (float*)alloc((size_t)N_NODES * 4);
    float* rbuf       = (float*)alloc((size_t)N_NODES * 4);
    float* score      = (float*)alloc((size_t)N_NODES * 4);
    int*   start      = (int*)  alloc((size_t)(N_GRAPHS + 1) * 4);

    k_gemm_bhist      <<<GEMM_BLOCKS + EB, 256, 0, stream>>>(x, Wl, Wr, ei, xr, xlb, bhist);
    k_colprefix_bounds<<<CPW_BLOCKS + NODE_BLOCKS, 256, 0, stream>>>(bhist, colsum, batch, start);
    k_bscatter        <<<EB, 256, 0, stream>>>(ei, bhist, colsum, colbase, bpack);
    k_fine            <<<NB, 256, 0, stream>>>(bpack, colbase, rowptr, sorted_src);
    k_gat             <<<(N_NODES + 3) / 4, 256, 0, stream>>>(xlb, xr, rowptr, sorted_src, att, bias,
                                                              w_rel, w_root, hfeat, tbuf, rbuf);
    k_pool            <<<N_GRAPHS, 256, 0, stream>>>(rowptr, sorted_src, tbuf, rbuf, b_sc,
                                                     score, hfeat, start, (float*)d_out);
}